// Round 1
// baseline (182.437 us; speedup 1.0000x reference)
//
#include <hip/hip_runtime.h>
#include <cstdint>
#include <cstddef>

// Problem dims
#define Bb 2
#define Ss 2048
#define Dd 1024
#define Hh 16
#define DKk 64

typedef unsigned short ushort_t;
typedef __bf16 bf16x8 __attribute__((ext_vector_type(8)));
typedef float f32x4 __attribute__((ext_vector_type(4)));
typedef unsigned short us8 __attribute__((ext_vector_type(8)));
typedef unsigned short us4 __attribute__((ext_vector_type(4)));

__device__ __forceinline__ ushort_t f2bf(float f) {
  __bf16 h = (__bf16)f;
  return __builtin_bit_cast(unsigned short, h);
}

// global -> LDS direct copy, 16B per lane. LDS dest must be wave-uniform;
// HW writes lane l's data at ldsbase + l*16.
__device__ __forceinline__ void gload_lds16(const void* g, void* l) {
  __builtin_amdgcn_global_load_lds(
      (__attribute__((address_space(1))) void*)(g),
      (__attribute__((address_space(3))) void*)(l),
      16, 0, 0);
}

// ---------------------------------------------------------------- cast fp32->bf16
__global__ __launch_bounds__(256) void cast_k(const float* __restrict__ s,
                                              ushort_t* __restrict__ d, int n8) {
  const int i = blockIdx.x * 256 + threadIdx.x;
  if (i >= n8) return;
  const float4* sp = (const float4*)s;
  float4 a = sp[2 * i], b = sp[2 * i + 1];
  us8 o;
  o[0] = f2bf(a.x); o[1] = f2bf(a.y); o[2] = f2bf(a.z); o[3] = f2bf(a.w);
  o[4] = f2bf(b.x); o[5] = f2bf(b.y); o[6] = f2bf(b.z); o[7] = f2bf(b.w);
  ((us8*)d)[i] = o;
}

// ---------------------------------------------------------------- GEMM
// y[m][n] = sum_k A[m][k] * W[n][k]  (both row-major, K contiguous)
// MODE 0: QKV projection. N=3072 (wq|wk|wv packed). Epilogue adds bias,
//         scales Q by 0.125, writes Q,K as [b,h,s,dk] bf16 and V transposed
//         as VT [b,h,dk,s] bf16.
// MODE 1: output projection. N=1024. Epilogue adds bias, writes fp32 [m][n].
template <int MODE>
__global__ __launch_bounds__(256) void gemm_k(
    const ushort_t* __restrict__ A, const ushort_t* __restrict__ W,
    const float* __restrict__ b0, const float* __restrict__ b1,
    const float* __restrict__ b2,
    ushort_t* __restrict__ oQ, ushort_t* __restrict__ oK,
    ushort_t* __restrict__ oVT, float* __restrict__ oF) {
  constexpr int Kd = 1024;
  __shared__ ushort_t As[128 * 32];
  __shared__ ushort_t Bs[128 * 32];
  const int tid = threadIdx.x;
  const int lane = tid & 63;
  const int wave = tid >> 6;
  const int m0 = blockIdx.y * 128;
  const int n0 = blockIdx.x * 128;
  const int lr = lane & 15;
  const int lg = lane >> 4;
  const int srow = lane >> 2;        // staging row within 16-row segment
  const int scol = (lane & 3) * 8;   // staging col (elements)
  const int ar = (wave >> 1) * 64;   // wave's output row base in tile
  const int bc = (wave & 1) * 64;    // wave's output col base in tile

  f32x4 acc[4][4] = {};

  for (int kt = 0; kt < Kd / 32; ++kt) {
    const int k0 = kt * 32;
#pragma unroll
    for (int c = 0; c < 2; ++c) {
      const int seg = wave * 2 + c;  // 0..7, 16 rows (1KB) each
      const int row = seg * 16 + srow;
      gload_lds16(A + (size_t)(m0 + row) * Kd + k0 + scol, (char*)As + seg * 1024);
      gload_lds16(W + (size_t)(n0 + row) * Kd + k0 + scol, (char*)Bs + seg * 1024);
    }
    __syncthreads();  // drains vmcnt before barrier
    bf16x8 af[4], bfr[4];
#pragma unroll
    for (int i = 0; i < 4; ++i)
      af[i] = *(const bf16x8*)&As[(ar + i * 16 + lr) * 32 + lg * 8];
#pragma unroll
    for (int j = 0; j < 4; ++j)
      bfr[j] = *(const bf16x8*)&Bs[(bc + j * 16 + lr) * 32 + lg * 8];
#pragma unroll
    for (int i = 0; i < 4; ++i)
#pragma unroll
      for (int j = 0; j < 4; ++j)
        acc[i][j] = __builtin_amdgcn_mfma_f32_16x16x32_bf16(af[i], bfr[j],
                                                            acc[i][j], 0, 0, 0);
    __syncthreads();
  }

  // Epilogue. C/D layout: reg r -> row (lg*4 + r), col = lr  [m89-verified]
#pragma unroll
  for (int i = 0; i < 4; ++i) {
    const int mrow = m0 + ar + i * 16 + lg * 4;  // + r
#pragma unroll
    for (int j = 0; j < 4; ++j) {
      const int n = n0 + bc + j * 16 + lr;
      if (MODE == 0) {
        const int sel = n >> 10;       // 0=Q 1=K 2=V (uniform per j)
        const int nn = n & 1023;
        const float bias = (sel == 0 ? b0 : sel == 1 ? b1 : b2)[nn];
        const int h = nn >> 6, dk = nn & 63;
        const int bidx = mrow >> 11;
        const int s = mrow & 2047;     // rows s..s+3 stay in same batch
        const int bh = bidx * Hh + h;
        if (sel == 2) {
          // V transposed: VT[bh][dk][s], 4 consecutive s -> one 8B store
          us4 pk;
#pragma unroll
          for (int r = 0; r < 4; ++r) pk[r] = f2bf(acc[i][j][r] + bias);
          *(us4*)&oVT[((size_t)bh * DKk + dk) * Ss + s] = pk;
        } else {
          ushort_t* dst = (sel == 0) ? oQ : oK;
          const float mul = (sel == 0) ? 0.125f : 1.0f;  // fold 1/sqrt(DK) into Q
#pragma unroll
          for (int r = 0; r < 4; ++r)
            dst[((size_t)bh * Ss + (s + r)) * DKk + dk] =
                f2bf((acc[i][j][r] + bias) * mul);
        }
      } else {
        const float bias = b0[n];
#pragma unroll
        for (int r = 0; r < 4; ++r)
          oF[(size_t)(mrow + r) * Dd + n] = acc[i][j][r] + bias;
      }
    }
  }
}

// ---------------------------------------------------------------- flash attention
// 1 wave = 32 q rows of one (b,h). KV tiles of 64. K, VT read from global
// (512KB/head, L2-resident). Online softmax; P re-layout via per-wave LDS.
__global__ __launch_bounds__(256) void attn_k(const ushort_t* __restrict__ Qg,
                                              const ushort_t* __restrict__ Kg,
                                              const ushort_t* __restrict__ Vt,
                                              ushort_t* __restrict__ AO) {
  __shared__ ushort_t Pl[4][32 * 72];  // stride 72 elems: ~2-way bank conflict only
  const int tid = threadIdx.x, lane = tid & 63, wave = tid >> 6;
  const int qt = 63 - (int)(blockIdx.x >> 3);  // heavy q-tiles scheduled first
  const int bh = ((blockIdx.x & 7) << 2) | wave;
  const int q0 = qt * 32;
  const int lr = lane & 15, lg = lane >> 4;
  const ushort_t* Qp = Qg + (size_t)bh * Ss * DKk;
  const ushort_t* Kp = Kg + (size_t)bh * Ss * DKk;
  const ushort_t* Vp = Vt + (size_t)bh * DKk * Ss;
  ushort_t* P = Pl[wave];

  bf16x8 qf[2][2];  // Q rows q0+rt*16+lr, d = ks*32 + lg*8 .. +8
#pragma unroll
  for (int rt = 0; rt < 2; ++rt)
#pragma unroll
    for (int ks = 0; ks < 2; ++ks)
      qf[rt][ks] =
          *(const bf16x8*)&Qp[(size_t)(q0 + rt * 16 + lr) * DKk + ks * 32 + lg * 8];

  f32x4 o[2][4] = {};
  float m_[2][4], l_[2][4];
#pragma unroll
  for (int rt = 0; rt < 2; ++rt)
#pragma unroll
    for (int r = 0; r < 4; ++r) { m_[rt][r] = -3e38f; l_[rt][r] = 0.f; }

  const int nt = (q0 >> 6) + 1;
  for (int t = 0; t < nt; ++t) {
    const int j0 = t * 64;
    // ---- S = Q K^T (Q pre-scaled by 1/8)
    f32x4 sc[2][4] = {};
#pragma unroll
    for (int ct = 0; ct < 4; ++ct) {
      const bf16x8 k0v =
          *(const bf16x8*)&Kp[(size_t)(j0 + ct * 16 + lr) * DKk + lg * 8];
      const bf16x8 k1v =
          *(const bf16x8*)&Kp[(size_t)(j0 + ct * 16 + lr) * DKk + 32 + lg * 8];
#pragma unroll
      for (int rt = 0; rt < 2; ++rt) {
        sc[rt][ct] = __builtin_amdgcn_mfma_f32_16x16x32_bf16(qf[rt][0], k0v,
                                                             sc[rt][ct], 0, 0, 0);
        sc[rt][ct] = __builtin_amdgcn_mfma_f32_16x16x32_bf16(qf[rt][1], k1v,
                                                             sc[rt][ct], 0, 0, 0);
      }
    }
    // ---- causal mask (only the diagonal tile has masked elements)
    if (t == nt - 1) {
#pragma unroll
      for (int rt = 0; rt < 2; ++rt)
#pragma unroll
        for (int ct = 0; ct < 4; ++ct)
#pragma unroll
          for (int r = 0; r < 4; ++r) {
            const int qi = q0 + rt * 16 + lg * 4 + r;
            const int kj = j0 + ct * 16 + lr;
            if (kj > qi) sc[rt][ct][r] = -1e30f;
          }
    }
    // ---- online softmax (rows distributed: row = rt*16+lg*4+r, 16 lanes/row)
    float fsc[2][4];
#pragma unroll
    for (int rt = 0; rt < 2; ++rt) {
#pragma unroll
      for (int r = 0; r < 4; ++r) {
        float mx = fmaxf(fmaxf(sc[rt][0][r], sc[rt][1][r]),
                         fmaxf(sc[rt][2][r], sc[rt][3][r]));
#pragma unroll
        for (int d = 1; d < 16; d <<= 1) mx = fmaxf(mx, __shfl_xor(mx, d, 64));
        const float mnew = fmaxf(m_[rt][r], mx);
        const float f = __expf(m_[rt][r] - mnew);
        m_[rt][r] = mnew;
        float rs = 0.f;
#pragma unroll
        for (int ct = 0; ct < 4; ++ct) {
          const float p = __expf(sc[rt][ct][r] - mnew);
          rs += p;
          P[(rt * 16 + lg * 4 + r) * 72 + ct * 16 + lr] = f2bf(p);
        }
#pragma unroll
        for (int d = 1; d < 16; d <<= 1) rs += __shfl_xor(rs, d, 64);
        l_[rt][r] = l_[rt][r] * f + rs;
        fsc[rt][r] = f;
      }
    }
    // ---- rescale O
#pragma unroll
    for (int rt = 0; rt < 2; ++rt)
#pragma unroll
      for (int dj = 0; dj < 4; ++dj)
#pragma unroll
        for (int r = 0; r < 4; ++r) o[rt][dj][r] *= fsc[rt][r];
    // LDS write->read ordering within the wave
    asm volatile("s_waitcnt lgkmcnt(0)" ::: "memory");
    // ---- O += P V   (A-op = P rows q, B-op from VT rows d)
    bf16x8 pa[2][2];
#pragma unroll
    for (int rt = 0; rt < 2; ++rt)
#pragma unroll
      for (int ksp = 0; ksp < 2; ++ksp)
        pa[rt][ksp] = *(const bf16x8*)&P[(rt * 16 + lr) * 72 + ksp * 32 + lg * 8];
#pragma unroll
    for (int dj = 0; dj < 4; ++dj) {
#pragma unroll
      for (int ksp = 0; ksp < 2; ++ksp) {
        const bf16x8 vv = *(const bf16x8*)&Vp[(size_t)(dj * 16 + lr) * Ss + j0 +
                                              ksp * 32 + lg * 8];
#pragma unroll
        for (int rt = 0; rt < 2; ++rt)
          o[rt][dj] = __builtin_amdgcn_mfma_f32_16x16x32_bf16(pa[rt][ksp], vv,
                                                              o[rt][dj], 0, 0, 0);
      }
    }
  }
  // ---- normalize and write AO [b*S+s][h*64+d] bf16 (ready for out-projection)
  const int bb = bh >> 4, hh = bh & 15;
#pragma unroll
  for (int rt = 0; rt < 2; ++rt) {
#pragma unroll
    for (int r = 0; r < 4; ++r) {
      const float inv = 1.0f / l_[rt][r];
      const int m = bb * Ss + q0 + rt * 16 + lg * 4 + r;
#pragma unroll
      for (int dj = 0; dj < 4; ++dj)
        AO[(size_t)m * Dd + hh * 64 + dj * 16 + lr] = f2bf(o[rt][dj][r] * inv);
    }
  }
}

// ---------------------------------------------------------------- launch
extern "C" void kernel_launch(void* const* d_in, const int* in_sizes, int n_in,
                              void* d_out, int out_size, void* d_ws, size_t ws_size,
                              hipStream_t stream) {
  const float* x  = (const float*)d_in[0];
  // d_in[1] = causal mask (tril) — hardcoded in attn kernel
  const float* wq = (const float*)d_in[2];
  const float* bq = (const float*)d_in[3];
  const float* wk = (const float*)d_in[4];
  const float* bk = (const float*)d_in[5];
  const float* wv = (const float*)d_in[6];
  const float* bv = (const float*)d_in[7];
  const float* wo = (const float*)d_in[8];
  const float* bo = (const float*)d_in[9];

  ushort_t* ws   = (ushort_t*)d_ws;
  ushort_t* xb   = ws;                   // [4096][1024] bf16 (8MB), reused as AO
  ushort_t* wqkv = xb + 4096 * 1024;     // [3072][1024] bf16 (6MB)
  ushort_t* wob  = wqkv + 3072 * 1024;   // [1024][1024] bf16 (2MB)
  ushort_t* Qb   = wob + 1024 * 1024;    // [2,16,2048,64] bf16 (8MB)
  ushort_t* Kb   = Qb + 4194304;         // (8MB)
  ushort_t* VTb  = Kb + 4194304;         // [2,16,64,2048] bf16 (8MB)
  ushort_t* AOb  = xb;                   // reuse: x dead after QKV GEMM

  cast_k<<<2048, 256, 0, stream>>>(x, xb, 524288);
  cast_k<<<512, 256, 0, stream>>>(wq, wqkv, 131072);
  cast_k<<<512, 256, 0, stream>>>(wk, wqkv + 1048576, 131072);
  cast_k<<<512, 256, 0, stream>>>(wv, wqkv + 2097152, 131072);
  cast_k<<<512, 256, 0, stream>>>(wo, wob, 131072);

  gemm_k<0><<<dim3(24, 32), 256, 0, stream>>>(xb, wqkv, bq, bk, bv, Qb, Kb, VTb,
                                              nullptr);
  attn_k<<<512, 256, 0, stream>>>(Qb, Kb, VTb, AOb);
  gemm_k<1><<<dim3(8, 32), 256, 0, stream>>>(AOb, wob, bo, nullptr, nullptr,
                                             nullptr, nullptr, nullptr,
                                             (float*)d_out);
}

// Round 2
// 152.796 us; speedup vs baseline: 1.1940x; 1.1940x over previous
//
#include <hip/hip_runtime.h>
#include <cstdint>
#include <cstddef>

// Problem dims
#define Bb 2
#define Ss 2048
#define Dd 1024
#define Hh 16
#define DKk 64

typedef unsigned short ushort_t;
typedef __bf16 bf16x8 __attribute__((ext_vector_type(8)));
typedef float f32x4 __attribute__((ext_vector_type(4)));
typedef unsigned short us8 __attribute__((ext_vector_type(8)));
typedef unsigned short us4 __attribute__((ext_vector_type(4)));

__device__ __forceinline__ ushort_t f2bf(float f) {
  __bf16 h = (__bf16)f;
  return __builtin_bit_cast(unsigned short, h);
}

// global -> LDS direct copy, 16B per lane. LDS dest must be wave-uniform;
// HW writes lane l's data at ldsbase + l*16.
__device__ __forceinline__ void gload_lds16(const void* g, void* l) {
  __builtin_amdgcn_global_load_lds(
      (__attribute__((address_space(1))) void*)(g),
      (__attribute__((address_space(3))) void*)(l),
      16, 0, 0);
}

// ---------------------------------------------------------------- cast fp32->bf16
__global__ __launch_bounds__(256) void cast_k(const float* __restrict__ s,
                                              ushort_t* __restrict__ d, int n8) {
  const int i = blockIdx.x * 256 + threadIdx.x;
  if (i >= n8) return;
  const float4* sp = (const float4*)s;
  float4 a = sp[2 * i], b = sp[2 * i + 1];
  us8 o;
  o[0] = f2bf(a.x); o[1] = f2bf(a.y); o[2] = f2bf(a.z); o[3] = f2bf(a.w);
  o[4] = f2bf(b.x); o[5] = f2bf(b.y); o[6] = f2bf(b.z); o[7] = f2bf(b.w);
  ((us8*)d)[i] = o;
}

// ---------------------------------------------------------------- GEMM
// y[m][n] = sum_k A[m][k] * W[n][k]  (both row-major, K contiguous)
// MODE 0: QKV projection. N=3072 (wq|wk|wv packed). Epilogue adds bias,
//         scales Q by 0.125, writes Q,K as [b,h,s,dk] bf16 and V transposed
//         as VT [b,h,dk,s] bf16.
// MODE 1: output projection. N=1024. Epilogue adds bias, writes fp32 [m][n].
template <int MODE>
__global__ __launch_bounds__(256) void gemm_k(
    const ushort_t* __restrict__ A, const ushort_t* __restrict__ W,
    const float* __restrict__ b0, const float* __restrict__ b1,
    const float* __restrict__ b2,
    ushort_t* __restrict__ oQ, ushort_t* __restrict__ oK,
    ushort_t* __restrict__ oVT, float* __restrict__ oF) {
  constexpr int Kd = 1024;
  __shared__ ushort_t As[128 * 32];
  __shared__ ushort_t Bs[128 * 32];
  const int tid = threadIdx.x;
  const int lane = tid & 63;
  const int wave = tid >> 6;
  const int m0 = blockIdx.y * 128;
  const int n0 = blockIdx.x * 128;
  const int lr = lane & 15;
  const int lg = lane >> 4;
  const int srow = lane >> 2;        // staging row within 16-row segment
  const int scol = (lane & 3) * 8;   // staging col (elements)
  const int ar = (wave >> 1) * 64;   // wave's output row base in tile
  const int bc = (wave & 1) * 64;    // wave's output col base in tile

  f32x4 acc[4][4] = {};

  for (int kt = 0; kt < Kd / 32; ++kt) {
    const int k0 = kt * 32;
#pragma unroll
    for (int c = 0; c < 2; ++c) {
      const int seg = wave * 2 + c;  // 0..7, 16 rows (1KB) each
      const int row = seg * 16 + srow;
      gload_lds16(A + (size_t)(m0 + row) * Kd + k0 + scol, (char*)As + seg * 1024);
      gload_lds16(W + (size_t)(n0 + row) * Kd + k0 + scol, (char*)Bs + seg * 1024);
    }
    __syncthreads();  // drains vmcnt before barrier
    bf16x8 af[4], bfr[4];
#pragma unroll
    for (int i = 0; i < 4; ++i)
      af[i] = *(const bf16x8*)&As[(ar + i * 16 + lr) * 32 + lg * 8];
#pragma unroll
    for (int j = 0; j < 4; ++j)
      bfr[j] = *(const bf16x8*)&Bs[(bc + j * 16 + lr) * 32 + lg * 8];
#pragma unroll
    for (int i = 0; i < 4; ++i)
#pragma unroll
      for (int j = 0; j < 4; ++j)
        acc[i][j] = __builtin_amdgcn_mfma_f32_16x16x32_bf16(af[i], bfr[j],
                                                            acc[i][j], 0, 0, 0);
    __syncthreads();
  }

  // Epilogue. C/D layout: reg r -> row (lg*4 + r), col = lr  [m89-verified]
#pragma unroll
  for (int i = 0; i < 4; ++i) {
    const int mrow = m0 + ar + i * 16 + lg * 4;  // + r
#pragma unroll
    for (int j = 0; j < 4; ++j) {
      const int n = n0 + bc + j * 16 + lr;
      if (MODE == 0) {
        const int sel = n >> 10;       // 0=Q 1=K 2=V (uniform per j)
        const int nn = n & 1023;
        const float bias = (sel == 0 ? b0 : sel == 1 ? b1 : b2)[nn];
        const int h = nn >> 6, dk = nn & 63;
        const int bidx = mrow >> 11;
        const int s = mrow & 2047;     // rows s..s+3 stay in same batch
        const int bh = bidx * Hh + h;
        if (sel == 2) {
          // V transposed: VT[bh][dk][s], 4 consecutive s -> one 8B store
          us4 pk;
#pragma unroll
          for (int r = 0; r < 4; ++r) pk[r] = f2bf(acc[i][j][r] + bias);
          *(us4*)&oVT[((size_t)bh * DKk + dk) * Ss + s] = pk;
        } else {
          ushort_t* dst = (sel == 0) ? oQ : oK;
          const float mul = (sel == 0) ? 0.125f : 1.0f;  // fold 1/sqrt(DK) into Q
#pragma unroll
          for (int r = 0; r < 4; ++r)
            dst[((size_t)bh * Ss + (s + r)) * DKk + dk] =
                f2bf((acc[i][j][r] + bias) * mul);
        }
      } else {
        const float bias = b0[n];
#pragma unroll
        for (int r = 0; r < 4; ++r)
          oF[(size_t)(mrow + r) * Dd + n] = acc[i][j][r] + bias;
      }
    }
  }
}

// ---------------------------------------------------------------- flash attention
// Block = 4 waves = 64 consecutive q rows of one (b,h); wave w owns 16 rows.
// All 4 waves share the K tile (64x64 bf16), double-buffered in LDS, staged
// with global_load_lds (next tile staged while computing current). K LDS is
// XOR-swizzled (slot ^= row&7) via pre-swizzled global source (rule 21).
// VT is prefetched into registers at iteration start (consumed post-softmax).
// Row-sum l computed by an extra MFMA with an all-ones B operand.
__global__ __launch_bounds__(256, 4) void attn_k(const ushort_t* __restrict__ Qg,
                                                 const ushort_t* __restrict__ Kg,
                                                 const ushort_t* __restrict__ Vt,
                                                 ushort_t* __restrict__ AO) {
  __shared__ ushort_t Ks[2][64 * 64];   // 16 KB, double-buffered K tile
  __shared__ ushort_t Pl[4][16 * 72];   // 9 KB, per-wave P (stride 72: 2-way wr)
  const int tid = threadIdx.x, lane = tid & 63, wave = tid >> 6;
  const int bx = blockIdx.x;
  // balanced mapping: blocks {bx, bx+256, bx+512, bx+768} (one CU under
  // round-robin fill) get q-groups summing to equal work.
  const int r_ = bx >> 8;            // 0..3
  const int i_ = bx & 255;
  const int bh = i_ & 31;
  const int sub = i_ >> 5;           // 0..7
  const int g = 8 * r_ + ((r_ & 1) ? (7 - sub) : sub);  // q-group 0..31
  const int lr = lane & 15, lg = lane >> 4;
  const ushort_t* Qp = Qg + (size_t)bh * Ss * DKk;
  const ushort_t* Kp = Kg + (size_t)bh * Ss * DKk;
  const ushort_t* Vp = Vt + (size_t)bh * DKk * Ss;
  ushort_t* P = Pl[wave];
  const int q0 = g * 64 + wave * 16;  // wave's 16 q rows
  const int nt = g + 1;               // KV tiles of 64

  // stage K tile t into Ks[buf]: wave stages rows wave*16..+15, 2 issues.
  // LDS linear; global source pre-swizzled: slot ^= (row&7).
  const int s_row = lane >> 3;                  // 0..7 within 8-row chunk
  const int s_slot = (lane & 7) ^ s_row;        // pre-swizzled 16B slot
  auto stageK = [&](int t, int buf) {
    const int j0t = t * 64;
    const int rb = wave * 16;
#pragma unroll
    for (int c = 0; c < 2; ++c) {
      gload_lds16(Kp + (size_t)(j0t + rb + c * 8 + s_row) * DKk + s_slot * 8,
                  &Ks[buf][(rb + c * 8) * 64]);
    }
  };

  stageK(0, 0);

  // Q fragment: rows q0+lr, k = ks*32 + lg*8
  bf16x8 qf[2];
#pragma unroll
  for (int ks = 0; ks < 2; ++ks)
    qf[ks] = *(const bf16x8*)&Qp[(size_t)(q0 + lr) * DKk + ks * 32 + lg * 8];

  bf16x8 onesv;
#pragma unroll
  for (int e = 0; e < 8; ++e) onesv[e] = (__bf16)1.0f;

  f32x4 o[4] = {};
  f32x4 l4 = {};
  float m_[4];
#pragma unroll
  for (int r = 0; r < 4; ++r) m_[r] = -3e38f;

  __syncthreads();  // K tile 0 staged (syncthreads drains vmcnt)

  for (int t = 0; t < nt; ++t) {
    const int j0 = t * 64;
    const int cb = t & 1;
    if (t + 1 < nt) stageK(t + 1, cb ^ 1);
    // VT prefetch for this tile (consumed after softmax)
    bf16x8 vt[4][2];
#pragma unroll
    for (int dj = 0; dj < 4; ++dj)
#pragma unroll
      for (int ksp = 0; ksp < 2; ++ksp)
        vt[dj][ksp] = *(const bf16x8*)&Vp[(size_t)(dj * 16 + lr) * Ss + j0 +
                                          ksp * 32 + lg * 8];
    const bool diag = (t == nt - 1);
    const int ctmax = diag ? wave : 3;  // ct > wave fully masked on diag tile
    // ---- S = Q K^T  (K from swizzled LDS)
    f32x4 sc[4];
    const int sw = lr & 7;
#pragma unroll
    for (int ct = 0; ct < 4; ++ct) {
      if (ct <= ctmax) {
        const int krow = ct * 16 + lr;
        const bf16x8 k0v = *(const bf16x8*)&Ks[cb][krow * 64 + ((lg ^ sw) * 8)];
        const bf16x8 k1v =
            *(const bf16x8*)&Ks[cb][krow * 64 + (((4 ^ lg) ^ sw) * 8)];
        f32x4 z = {};
        z = __builtin_amdgcn_mfma_f32_16x16x32_bf16(qf[0], k0v, z, 0, 0, 0);
        z = __builtin_amdgcn_mfma_f32_16x16x32_bf16(qf[1], k1v, z, 0, 0, 0);
        sc[ct] = z;
      } else {
        sc[ct] = (f32x4){-1e30f, -1e30f, -1e30f, -1e30f};
      }
    }
    // element-wise causal mask: only sub-tile ct == wave on the diagonal
    if (diag) {
#pragma unroll
      for (int r = 0; r < 4; ++r)
        if (lr > lg * 4 + r) sc[wave][r] = -1e30f;
    }
    // ---- online softmax (row = lg*4+r; 16 lanes of same lg share a row)
    float fsc[4];
#pragma unroll
    for (int r = 0; r < 4; ++r) {
      float mx = fmaxf(fmaxf(sc[0][r], sc[1][r]), fmaxf(sc[2][r], sc[3][r]));
#pragma unroll
      for (int d = 1; d < 16; d <<= 1) mx = fmaxf(mx, __shfl_xor(mx, d, 64));
      const float mnew = fmaxf(m_[r], mx);
      fsc[r] = __expf(m_[r] - mnew);
      m_[r] = mnew;
#pragma unroll
      for (int ct = 0; ct < 4; ++ct)
        P[(lg * 4 + r) * 72 + ct * 16 + lr] = f2bf(__expf(sc[ct][r] - mnew));
    }
    // ---- rescale O and l
#pragma unroll
    for (int dj = 0; dj < 4; ++dj)
#pragma unroll
      for (int r = 0; r < 4; ++r) o[dj][r] *= fsc[r];
#pragma unroll
    for (int r = 0; r < 4; ++r) l4[r] *= fsc[r];
    // LDS write->read ordering within the wave
    asm volatile("s_waitcnt lgkmcnt(0)" ::: "memory");
    bf16x8 pa[2];
#pragma unroll
    for (int ksp = 0; ksp < 2; ++ksp)
      pa[ksp] = *(const bf16x8*)&P[lr * 72 + ksp * 32 + lg * 8];
    // l += rowsum(P) via ones-operand MFMA (D = broadcast row sums)
    l4 = __builtin_amdgcn_mfma_f32_16x16x32_bf16(pa[0], onesv, l4, 0, 0, 0);
    l4 = __builtin_amdgcn_mfma_f32_16x16x32_bf16(pa[1], onesv, l4, 0, 0, 0);
    // ---- O += P V
#pragma unroll
    for (int dj = 0; dj < 4; ++dj)
#pragma unroll
      for (int ksp = 0; ksp < 2; ++ksp)
        o[dj] = __builtin_amdgcn_mfma_f32_16x16x32_bf16(pa[ksp], vt[dj][ksp],
                                                        o[dj], 0, 0, 0);
    __syncthreads();  // K stage(t+1) complete (vmcnt0) + buffer handoff
  }
  // ---- normalize and write AO [b*S+s][h*64+d] bf16
  const int bb = bh >> 4, hh = bh & 15;
#pragma unroll
  for (int r = 0; r < 4; ++r) {
    const float inv = 1.0f / l4[r];
    const size_t m = (size_t)bb * Ss + q0 + lg * 4 + r;
#pragma unroll
    for (int dj = 0; dj < 4; ++dj)
      AO[m * Dd + hh * 64 + dj * 16 + lr] = f2bf(o[dj][r] * inv);
  }
}

// ---------------------------------------------------------------- launch
extern "C" void kernel_launch(void* const* d_in, const int* in_sizes, int n_in,
                              void* d_out, int out_size, void* d_ws, size_t ws_size,
                              hipStream_t stream) {
  const float* x  = (const float*)d_in[0];
  // d_in[1] = causal mask (tril) — hardcoded in attn kernel
  const float* wq = (const float*)d_in[2];
  const float* bq = (const float*)d_in[3];
  const float* wk = (const float*)d_in[4];
  const float* bk = (const float*)d_in[5];
  const float* wv = (const float*)d_in[6];
  const float* bv = (const float*)d_in[7];
  const float* wo = (const float*)d_in[8];
  const float* bo = (const float*)d_in[9];

  ushort_t* ws   = (ushort_t*)d_ws;
  ushort_t* xb   = ws;                   // [4096][1024] bf16 (8MB), reused as AO
  ushort_t* wqkv = xb + 4096 * 1024;     // [3072][1024] bf16 (6MB)
  ushort_t* wob  = wqkv + 3072 * 1024;   // [1024][1024] bf16 (2MB)
  ushort_t* Qb   = wob + 1024 * 1024;    // [2,16,2048,64] bf16 (8MB)
  ushort_t* Kb   = Qb + 4194304;         // (8MB)
  ushort_t* VTb  = Kb + 4194304;         // [2,16,64,2048] bf16 (8MB)
  ushort_t* AOb  = xb;                   // reuse: x dead after QKV GEMM

  cast_k<<<2048, 256, 0, stream>>>(x, xb, 524288);
  cast_k<<<512, 256, 0, stream>>>(wq, wqkv, 131072);
  cast_k<<<512, 256, 0, stream>>>(wk, wqkv + 1048576, 131072);
  cast_k<<<512, 256, 0, stream>>>(wv, wqkv + 2097152, 131072);
  cast_k<<<512, 256, 0, stream>>>(wo, wob, 131072);

  gemm_k<0><<<dim3(24, 32), 256, 0, stream>>>(xb, wqkv, bq, bk, bv, Qb, Kb, VTb,
                                              nullptr);
  attn_k<<<1024, 256, 0, stream>>>(Qb, Kb, VTb, AOb);
  gemm_k<1><<<dim3(8, 32), 256, 0, stream>>>(AOb, wob, bo, nullptr, nullptr,
                                             nullptr, nullptr, nullptr,
                                             (float*)d_out);
}